// Round 15
// baseline (635.145 us; speedup 1.0000x reference)
//
#include <hip/hip_runtime.h>
#include <math.h>

#define BB 2
#define TT 2048
#define DD 512
#define LL 4
#define HH 8
#define HDD 64
#define SEMN 50
#define CLIPN 512
#define NTOK (BB*TT)   // 4096
#define QS 1024        // qkv buffer row stride (Q|K only; V goes transposed)
#define VST 2056       // vt key-stride (2048 + 8, breaks 4KB aliasing)

typedef __bf16 bf16x8 __attribute__((ext_vector_type(8)));
typedef __bf16 bf16x4 __attribute__((ext_vector_type(4)));
typedef float  f32x4  __attribute__((ext_vector_type(4)));

#if __has_builtin(__builtin_amdgcn_global_load_lds)
#define USE_GLL 1
#endif

__device__ __forceinline__ void gll16(const __bf16* g, __bf16* l) {
#ifdef USE_GLL
  __builtin_amdgcn_global_load_lds((const __attribute__((address_space(1))) void*)g,
                                   (__attribute__((address_space(3))) void*)l, 16, 0, 0);
#endif
}

__device__ __forceinline__ float fexp2(float x) {
#if __has_builtin(__builtin_amdgcn_exp2f)
  return __builtin_amdgcn_exp2f(x);
#else
  return exp2f(x);
#endif
}

// ---------------- embedding (t>=1 rows): gather + pos, float4 ----------------
__global__ __launch_bounds__(128) void embed_kernel(
    const int* __restrict__ idx,
    const float* __restrict__ tok0, const float* __restrict__ tok1,
    const float* __restrict__ pos, float* __restrict__ x) {
  int row = blockIdx.x;
  int b = row / TT, t = row % TT;
  if (t == 0) return;                  // cond_kernel covers t==0
  int d4 = threadIdx.x << 2;
  int tok = idx[b*(TT-1) + (t-1)];
  const float* te = (t <= SEMN) ? tok0 : tok1;
  float4 e = *(const float4*)&te[(size_t)tok*DD + d4];
  float4 p = *(const float4*)&pos[(size_t)t*DD + d4];
  e.x += p.x; e.y += p.y; e.z += p.z; e.w += p.w;
  *(float4*)&x[(size_t)row*DD + d4] = e;
}

// ---------------- cond matvec (t==0 rows): k-split 8x + LDS reduce ----------------
__global__ __launch_bounds__(256) void cond_kernel(
    const float* __restrict__ clip, const float* __restrict__ cw,
    const float* __restrict__ cb, const float* __restrict__ pos,
    float* __restrict__ x) {
  __shared__ float4 part[8][32];
  int b = blockIdx.x >> 2, dc = blockIdx.x & 3;   // d-chunk of 128
  int tid = threadIdx.x;
  int dv = tid & 31;                  // float4 index within chunk
  int cg = tid >> 5;                  // k-group 0..7 (64 c each)
  int d4 = dc*128 + dv*4;
  const float* cr = clip + b*CLIPN + cg*64;
  float4 acc = {0.f, 0.f, 0.f, 0.f};
  #pragma unroll 8
  for (int i = 0; i < 64; ++i) {
    float cv = cr[i];
    float4 w4 = *(const float4*)&cw[(size_t)(cg*64 + i)*DD + d4];
    acc.x = fmaf(cv, w4.x, acc.x); acc.y = fmaf(cv, w4.y, acc.y);
    acc.z = fmaf(cv, w4.z, acc.z); acc.w = fmaf(cv, w4.w, acc.w);
  }
  part[cg][dv] = acc;
  __syncthreads();
  if (tid < 32) {
    int dd4 = dc*128 + tid*4;
    float4 s = part[0][tid];
    #pragma unroll
    for (int g = 1; g < 8; ++g) {
      float4 q = part[g][tid];
      s.x += q.x; s.y += q.y; s.z += q.z; s.w += q.w;
    }
    float4 cbv = *(const float4*)&cb[dd4];
    float4 pv  = *(const float4*)&pos[dd4];      // pos row 0
    s.x += cbv.x + pv.x; s.y += cbv.y + pv.y;
    s.z += cbv.z + pv.z; s.w += cbv.w + pv.w;
    *(float4*)&x[(size_t)(b*TT)*DD + dd4] = s;
  }
}

// ---------------- weight transpose+convert: [K,N] f32 -> [N,K] bf16; gridDim.y = layers ----------------
__global__ __launch_bounds__(256) void prep_kernel(
    const float* __restrict__ wq, const float* __restrict__ wk,
    const float* __restrict__ wv, const float* __restrict__ wo,
    const float* __restrict__ w1, const float* __restrict__ w2,
    __bf16* __restrict__ wbuf, size_t dstride) {
  __shared__ float tile[32][33];
  int id = blockIdx.x;
  int lay = blockIdx.y;
  size_t so4 = (size_t)lay * 262144, so16 = (size_t)lay * 1048576;
  __bf16* wb = wbuf + (size_t)lay * dstride;
  const float* src; __bf16* dst; int K, N, t;
  if (id < 1024) {
    int m = id >> 8; t = id & 255;
    src = ((m==0) ? wq : (m==1) ? wk : (m==2) ? wv : wo) + so4;
    dst = wb + (size_t)m * 262144; K = 512; N = 512;
  } else if (id < 2048) {
    t = id - 1024; src = w1 + so16; dst = wb + 1048576; K = 512; N = 2048;
  } else {
    t = id - 2048; src = w2 + so16; dst = wb + 2097152; K = 2048; N = 512;
  }
  int nsh = (N == 2048) ? 6 : 4;
  int tk = t >> nsh, tn = t & ((1 << nsh) - 1);
  int k0 = tk << 5, n0 = tn << 5;
  int tid = threadIdx.x;
  int r = tid >> 3, c = (tid & 7) << 2;
  float4 v = *(const float4*)&src[(size_t)(k0 + r)*N + n0 + c];
  tile[r][c+0] = v.x; tile[r][c+1] = v.y; tile[r][c+2] = v.z; tile[r][c+3] = v.w;
  __syncthreads();
  bf16x4 o;
  o[0] = (__bf16)tile[c+0][r];
  o[1] = (__bf16)tile[c+1][r];
  o[2] = (__bf16)tile[c+2][r];
  o[3] = (__bf16)tile[c+3][r];
  *(bf16x4*)&dst[(size_t)(n0 + r)*K + k0 + c] = o;
}

// ---------------- bf16 MFMA GEMM, BK=64, single-buffer (R13 structure) ----------------
// FLN=1: A is fp32 x[M,512]; block computes LN stats for its TM rows in a prologue and
// applies (x-mean)*rstd*g+beta during reg-staged A->LDS conversion. B stays global_load_lds.
// 8-slot XOR swizzle (slot ^ row&7): on global source for gll (rule 21), on the LDS write
// address for the reg-staged A path (per-lane ds_write, no constraint).
template<int TM, int TN, int FLN, int QKV3, int RES, int GEL, int OB>
__global__ __launch_bounds__(256) void mgemm(
    const __bf16* __restrict__ A, const float* __restrict__ Af,
    const float* __restrict__ lng, const float* __restrict__ lnb,
    const __bf16* __restrict__ Bt,
    const float* __restrict__ b0, const float* __restrict__ b1p, const float* __restrict__ b2p,
    const float* __restrict__ res, float* __restrict__ outF, __bf16* __restrict__ outB,
    __bf16* __restrict__ vtOut, int M, int N, int K, int ldo) {
  __shared__ __bf16 As[TM*64];
  __shared__ __bf16 Bs[TN*64];
  __shared__ float ps[FLN ? TM : 1][4][2];
  __shared__ float rowm[FLN ? TM : 1], rowr[FLN ? TM : 1];
  int tid = threadIdx.x, wave = tid >> 6, l = tid & 63;
  int l15 = l & 15, lg = l >> 4;
  int m0 = blockIdx.y * TM, n0 = blockIdx.x * TN;
  constexpr int WR = (TM == 128) ? 2 : 1;
  constexpr int WC = 4 / WR;
  constexpr int FM = TM / (16 * WR);
  constexpr int FN = TN / (16 * WC);
  int wr = wave / WC;
  int wc = wave % WC;

  f32x4 acc[FM][FN] = {};

  if (FLN) {
    // ---- LN stats prologue: row = tid>>2, quarter = tid&3 (128 cols each) ----
    int r = tid >> 2, qd = tid & 3;
    const float* xr = Af + (size_t)(m0 + r)*DD + qd*128;
    float s = 0.f, s2 = 0.f;
    #pragma unroll 8
    for (int i = 0; i < 32; ++i) {
      float4 v = *(const float4*)(xr + i*4);
      s  += v.x + v.y + v.z + v.w;
      s2 += v.x*v.x + v.y*v.y + v.z*v.z + v.w*v.w;
    }
    ps[r][qd][0] = s; ps[r][qd][1] = s2;
    __syncthreads();
    if (tid < TM) {
      float ss  = ps[tid][0][0] + ps[tid][1][0] + ps[tid][2][0] + ps[tid][3][0];
      float ss2 = ps[tid][0][1] + ps[tid][1][1] + ps[tid][2][1] + ps[tid][3][1];
      float mean = ss * (1.0f / DD);
      float var  = ss2 * (1.0f / DD) - mean*mean;
      rowm[tid] = mean;
      rowr[tid] = rsqrtf(var + 1e-5f);
    }
    // consumed after the staging barrier below
  }

  for (int k0 = 0; k0 < K; k0 += 64) {
    __syncthreads();    // previous tile consumed (and stats ready on first iter)
    if (FLN) {
      // reg-staged A with LN apply: row = tid>>2, two 8-elem slots sl, sl+1
      int row = tid >> 2;
      int sl = (tid & 3) << 1;
      const float* src = Af + (size_t)(m0 + row)*DD + k0 + sl*8;
      float mean = rowm[row], rstd = rowr[row];
      float4 v0 = *(const float4*)(src);
      float4 v1 = *(const float4*)(src + 4);
      float4 v2 = *(const float4*)(src + 8);
      float4 v3 = *(const float4*)(src + 12);
      float4 g0 = *(const float4*)&lng[k0 + sl*8];
      float4 g1 = *(const float4*)&lng[k0 + sl*8 + 4];
      float4 g2 = *(const float4*)&lng[k0 + sl*8 + 8];
      float4 g3 = *(const float4*)&lng[k0 + sl*8 + 12];
      float4 be0 = *(const float4*)&lnb[k0 + sl*8];
      float4 be1 = *(const float4*)&lnb[k0 + sl*8 + 4];
      float4 be2 = *(const float4*)&lnb[k0 + sl*8 + 8];
      float4 be3 = *(const float4*)&lnb[k0 + sl*8 + 12];
      bf16x8 o0, o1;
      o0[0] = (__bf16)((v0.x-mean)*rstd*g0.x + be0.x);
      o0[1] = (__bf16)((v0.y-mean)*rstd*g0.y + be0.y);
      o0[2] = (__bf16)((v0.z-mean)*rstd*g0.z + be0.z);
      o0[3] = (__bf16)((v0.w-mean)*rstd*g0.w + be0.w);
      o0[4] = (__bf16)((v1.x-mean)*rstd*g1.x + be1.x);
      o0[5] = (__bf16)((v1.y-mean)*rstd*g1.y + be1.y);
      o0[6] = (__bf16)((v1.z-mean)*rstd*g1.z + be1.z);
      o0[7] = (__bf16)((v1.w-mean)*rstd*g1.w + be1.w);
      o1[0] = (__bf16)((v2.x-mean)*rstd*g2.x + be2.x);
      o1[1] = (__bf16)((v2.y-mean)*rstd*g2.y + be2.y);
      o1[2] = (__bf16)((v2.z-mean)*rstd*g2.z + be2.z);
      o1[3] = (__bf16)((v2.w-mean)*rstd*g2.w + be2.w);
      o1[4] = (__bf16)((v3.x-mean)*rstd*g3.x + be3.x);
      o1[5] = (__bf16)((v3.y-mean)*rstd*g3.y + be3.y);
      o1[6] = (__bf16)((v3.z-mean)*rstd*g3.z + be3.z);
      o1[7] = (__bf16)((v3.w-mean)*rstd*g3.w + be3.w);
      *(bf16x8*)&As[row*64 + ((sl+0) ^ (row & 7))*8] = o0;
      *(bf16x8*)&As[row*64 + ((sl+1) ^ (row & 7))*8] = o1;
    }
#ifdef USE_GLL
    if (!FLN) {
      #pragma unroll
      for (int g = wave; g < TM/8; g += 4) {
        int row = g*8 + (l >> 3);
        int lslot = (l & 7) ^ (row & 7);
        gll16(A + (size_t)(m0+row)*K + k0 + lslot*8, &As[g*512]);
      }
    }
    #pragma unroll
    for (int g = wave; g < TN/8; g += 4) {
      int row = g*8 + (l >> 3);
      int lslot = (l & 7) ^ (row & 7);
      gll16(Bt + (size_t)(n0+row)*K + k0 + lslot*8, &Bs[g*512]);
    }
    asm volatile("s_waitcnt vmcnt(0)" ::: "memory");
    __syncthreads();
#else
    {
      bf16x8 br[TN/32];
      #pragma unroll
      for (int c = 0; c < TN/32; ++c) {
        int idx = tid + c*256;
        int row = idx >> 3;
        int lslot = (idx & 7) ^ (row & 7);
        br[c] = *(const bf16x8*)(Bt + (size_t)(n0+row)*K + k0 + lslot*8);
      }
      bf16x8 ar[TM/32];
      if (!FLN) {
        #pragma unroll
        for (int c = 0; c < TM/32; ++c) {
          int idx = tid + c*256;
          int row = idx >> 3;
          int lslot = (idx & 7) ^ (row & 7);
          ar[c] = *(const bf16x8*)(A + (size_t)(m0+row)*K + k0 + lslot*8);
        }
      }
      #pragma unroll
      for (int c = 0; c < TN/32; ++c) {
        int idx = tid + c*256;
        *(bf16x8*)&Bs[(idx >> 3)*64 + (idx & 7)*8] = br[c];
      }
      if (!FLN) {
        #pragma unroll
        for (int c = 0; c < TM/32; ++c) {
          int idx = tid + c*256;
          *(bf16x8*)&As[(idx >> 3)*64 + (idx & 7)*8] = ar[c];
        }
      }
      __syncthreads();
    }
#endif
    bf16x8 af[FM][2], bfr[FN][2];
    #pragma unroll
    for (int mi = 0; mi < FM; ++mi) {
      int row = (wr*FM + mi)*16 + l15;
      #pragma unroll
      for (int h = 0; h < 2; ++h) {
        int psl = (h*4 + lg) ^ (row & 7);
        af[mi][h] = *(const bf16x8*)&As[row*64 + psl*8];
      }
    }
    #pragma unroll
    for (int ni = 0; ni < FN; ++ni) {
      int row = (wc*FN + ni)*16 + l15;
      #pragma unroll
      for (int h = 0; h < 2; ++h) {
        int psl = (h*4 + lg) ^ (row & 7);
        bfr[ni][h] = *(const bf16x8*)&Bs[row*64 + psl*8];
      }
    }
    #pragma unroll
    for (int mi = 0; mi < FM; ++mi)
      #pragma unroll
      for (int ni = 0; ni < FN; ++ni) {
        acc[mi][ni] = __builtin_amdgcn_mfma_f32_16x16x32_bf16(af[mi][0], bfr[ni][0], acc[mi][ni], 0, 0, 0);
        acc[mi][ni] = __builtin_amdgcn_mfma_f32_16x16x32_bf16(af[mi][1], bfr[ni][1], acc[mi][ni], 0, 0, 0);
      }
  }

  #pragma unroll
  for (int mi = 0; mi < FM; ++mi) {
    #pragma unroll
    for (int ni = 0; ni < FN; ++ni) {
      int col = n0 + (wc*FN + ni)*16 + l15;
      float bs;
      if (QKV3) bs = (col < 512) ? b0[col] : (col < 1024) ? b1p[col-512] : b2p[col-1024];
      else bs = b0[col];
      int row0 = m0 + (wr*FM + mi)*16 + (lg << 2);
      if (QKV3 && col >= 1024) {
        int hdg = col - 1024;
        bf16x4 pk;
        #pragma unroll
        for (int r = 0; r < 4; ++r) pk[r] = (__bf16)(acc[mi][ni][r] + bs);
        size_t vrow = (size_t)(((row0 >> 11)*8 + (hdg >> 6))*64 + (hdg & 63));
        *(bf16x4*)&vtOut[vrow*VST + (row0 & 2047)] = pk;
      } else {
        #pragma unroll
        for (int r = 0; r < 4; ++r) {
          int row = row0 + r;
          float v = acc[mi][ni][r] + bs;
          if (RES) v += res[(size_t)row*ldo + col];
          if (GEL) v = 0.5f * v * (1.0f + erff(v * 0.70710678118654752f));
          if (OB) outB[(size_t)row*ldo + col] = (__bf16)v;
          else    outF[(size_t)row*ldo + col] = v;
        }
      }
    }
  }
}

// ---------------- flash attention: block = (b,h,32 q-rows), 4 waves key-split, KVBLK=64 ----------------
// Single K reg-buffer with EARLY RE-ISSUE (R13 structure, unchanged).
__global__ __launch_bounds__(256) void attn_kernel(const __bf16* __restrict__ qkv,
                                                   const __bf16* __restrict__ vt,
                                                   __bf16* __restrict__ y) {
  __shared__ float po[4][32][68];
  __shared__ float pmS[4][32];
  __shared__ float plS[4][4][32];
  int tid = threadIdx.x, wave = tid >> 6, l = tid & 63;
  int l15 = l & 15, lg = l >> 4;

  int wid = blockIdx.x;                // 0..1023, longest-first
  int g2 = 63 - (wid >> 4);            // 32-row q-group within (b,h)
  int bh = wid & 15;
  int b = bh >> 3, h = bh & 7;
  int q0 = g2 * 32;

  const __bf16* qp = qkv + (size_t)(b*TT)*QS + h*HDD;
  const __bf16* kp = qp + 512;
  const __bf16* vtp = vt + ((size_t)bh*64 + l15)*VST + lg*8;
  const __bf16* kbase = kp + (size_t)l15*QS + lg*8;

  // Q fragments, pre-scaled by log2(e)/sqrt(64)
  bf16x8 qf[2][2];
  {
    const float qs = 0.125f * 1.44269504088896f;
    #pragma unroll
    for (int f = 0; f < 2; ++f) {
      size_t qr = (size_t)(q0 + f*16 + l15) * QS + lg*8;
      bf16x8 t0 = *(const bf16x8*)(qp + qr);
      bf16x8 t1 = *(const bf16x8*)(qp + qr + 32);
      #pragma unroll
      for (int e = 0; e < 8; ++e) {
        qf[f][0][e] = (__bf16)((float)t0[e] * qs);
        qf[f][1][e] = (__bf16)((float)t1[e] * qs);
      }
    }
  }

  f32x4 o[2][4] = {};
  float m0 = 0.f, m1 = 0.f, ls0 = 0.f, ls1 = 0.f;
  int qpos0 = q0 + l15, qpos1 = q0 + 16 + l15;
  int nt = (q0 + 95) >> 6;             // ceil((q0+32)/64)
  int cs = (nt + 3) >> 2;
  int t0w = wave * cs;
  int t1w = t0w + cs; if (t1w > nt) t1w = nt;

  bf16x8 kf[4][2], vv[8];

#define KLOAD(KT) do {                                              \
    const __bf16* kr_ = kbase + (size_t)(KT)*64*QS;                 \
    _Pragma("unroll")                                               \
    for (int j_ = 0; j_ < 4; ++j_) {                                \
      kf[j_][0] = *(const bf16x8*)(kr_ + j_*16*QS);                 \
      kf[j_][1] = *(const bf16x8*)(kr_ + j_*16*QS + 32);            \
    }                                                               \
  } while (0)

#define VLOAD(KT) do {                                              \
    const __bf16* vr_ = vtp + (KT)*64;                              \
    _Pragma("unroll")                                               \
    for (int hc_ = 0; hc_ < 4; ++hc_) {                             \
      vv[hc_]     = *(const bf16x8*)(vr_ + hc_*16*VST);             \
      vv[hc_ + 4] = *(const bf16x8*)(vr_ + hc_*16*VST + 32);        \
    }                                                               \
  } while (0)

  if (t0w < t1w) {
    KLOAD(t0w);
    for (int kt = t0w; kt < t1w; ++kt) {
      VLOAD(kt);
      // ---- QK^T for both fragments (kf dead after this) ----
      float sv[2][4][4];
      #pragma unroll
      for (int f = 0; f < 2; ++f)
        #pragma unroll
        for (int j = 0; j < 4; ++j) {
          f32x4 a_ = {};
          a_ = __builtin_amdgcn_mfma_f32_16x16x32_bf16(kf[j][0], qf[f][0], a_, 0, 0, 0);
          a_ = __builtin_amdgcn_mfma_f32_16x16x32_bf16(kf[j][1], qf[f][1], a_, 0, 0, 0);
          #pragma unroll
          for (int r = 0; r < 4; ++r) sv[f][j][r] = a_[r];
        }
      // ---- early re-issue of next K tile; latency covered by softmax+PV below ----
      if (kt + 1 < t1w) KLOAD(kt + 1);
      // ---- causal mask (only the boundary tile needs it) ----
      if (kt == nt - 1) {
        #pragma unroll
        for (int j = 0; j < 4; ++j) {
          int kb0 = kt*64 + j*16 + lg*4;
          #pragma unroll
          for (int r = 0; r < 4; ++r) {
            if (kb0 + r > qpos0) sv[0][j][r] = -1e30f;
            if (kb0 + r > qpos1) sv[1][j][r] = -1e30f;
          }
        }
      }
      // ---- per-fragment softmax + PV ----
      #pragma unroll
      for (int f = 0; f < 2; ++f) {
        float& m  = f ? m1 : m0;
        float& ls = f ? ls1 : ls0;
        float px = sv[f][0][0];
        #pragma unroll
        for (int j = 0; j < 4; ++j)
          #pragma unroll
          for (int r = 0; r < 4; ++r) px = fmaxf(px, sv[f][j][r]);
        if (!__all(px - m <= 8.0f)) {
          float u = px, w = px;
          asm("v_permlane32_swap_b32 %0, %1" : "+v"(u), "+v"(w));
          float t_ = fmaxf(u, w); u = t_; w = t_;
          asm("v_permlane16_swap_b32 %0, %1" : "+v"(u), "+v"(w));
          float tm = fmaxf(u, w);
          float mn = fmaxf(m, tm);
          float fc = fexp2(m - mn);
          m = mn; ls *= fc;
          float f0_ = __shfl(fc, lg*4+0), f1_ = __shfl(fc, lg*4+1);
          float f2_ = __shfl(fc, lg*4+2), f3_ = __shfl(fc, lg*4+3);
          #pragma unroll
          for (int hc = 0; hc < 4; ++hc) {
            o[f][hc][0] *= f0_; o[f][hc][1] *= f1_;
            o[f][hc][2] *= f2_; o[f][hc][3] *= f3_;
          }
        }
        float p_[4][4];
        float rs = 0.f;
        #pragma unroll
        for (int j = 0; j < 4; ++j)
          #pragma unroll
          for (int r = 0; r < 4; ++r) { p_[j][r] = fexp2(sv[f][j][r] - m); rs += p_[j][r]; }
        ls += rs;
        union PU { unsigned u[4]; bf16x8 v; };
        PU pa0, pa1;
        #pragma unroll
        for (int pair = 0; pair < 2; ++pair) {
          unsigned c0, c1, d0, d1;
          asm("v_cvt_pk_bf16_f32 %0, %1, %2" : "=v"(c0) : "v"(p_[2*pair][0]),   "v"(p_[2*pair][1]));
          asm("v_cvt_pk_bf16_f32 %0, %1, %2" : "=v"(c1) : "v"(p_[2*pair][2]),   "v"(p_[2*pair][3]));
          asm("v_cvt_pk_bf16_f32 %0, %1, %2" : "=v"(d0) : "v"(p_[2*pair+1][0]), "v"(p_[2*pair+1][1]));
          asm("v_cvt_pk_bf16_f32 %0, %1, %2" : "=v"(d1) : "v"(p_[2*pair+1][2]), "v"(p_[2*pair+1][3]));
          asm("v_permlane32_swap_b32 %0, %1" : "+v"(c0), "+v"(d0));
          asm("v_permlane32_swap_b32 %0, %1" : "+v"(c1), "+v"(d1));
          asm("v_permlane16_swap_b32 %0, %1" : "+v"(c0), "+v"(d0));
          asm("v_permlane16_swap_b32 %0, %1" : "+v"(c1), "+v"(d1));
          PU& pa = pair ? pa1 : pa0;
          pa.u[0] = c0; pa.u[1] = c1; pa.u[2] = d0; pa.u[3] = d1;
        }
        #pragma unroll
        for (int hc = 0; hc < 4; ++hc) {
          o[f][hc] = __builtin_amdgcn_mfma_f32_16x16x32_bf16(pa0.v, vv[hc],     o[f][hc], 0, 0, 0);
          o[f][hc] = __builtin_amdgcn_mfma_f32_16x16x32_bf16(pa1.v, vv[hc + 4], o[f][hc], 0, 0, 0);
        }
      }
    }
  }

  // ---- write partials ----
  #pragma unroll
  for (int f = 0; f < 2; ++f)
    #pragma unroll
    for (int hc = 0; hc < 4; ++hc)
      #pragma unroll
      for (int r = 0; r < 4; ++r)
        po[wave][f*16 + lg*4 + r][hc*16 + l15] = o[f][hc][r];
  plS[wave][lg][l15]      = ls0;
  plS[wave][lg][16 + l15] = ls1;
  if (l < 16) { pmS[wave][l] = m0; pmS[wave][16 + l] = m1; }
  __syncthreads();

  // ---- flash merge (exp2 domain), two q-rows per thread ----
  #pragma unroll
  for (int rep = 0; rep < 2; ++rep) {
    int q = wave*4 + lg + rep*16;
    float e0 = pmS[0][q], e1 = pmS[1][q], e2 = pmS[2][q], e3 = pmS[3][q];
    float mstar = fmaxf(fmaxf(e0, e1), fmaxf(e2, e3));
    float f0 = fexp2(e0 - mstar), f1 = fexp2(e1 - mstar);
    float f2 = fexp2(e2 - mstar), f3 = fexp2(e3 - mstar);
    float l0 = plS[0][0][q] + plS[0][1][q] + plS[0][2][q] + plS[0][3][q];
    float l1 = plS[1][0][q] + plS[1][1][q] + plS[1][2][q] + plS[1][3][q];
    float l2 = plS[2][0][q] + plS[2][1][q] + plS[2][2][q] + plS[2][3][q];
    float l3 = plS[3][0][q] + plS[3][1][q] + plS[3][2][q] + plS[3][3][q];
    float lstar = l0*f0 + l1*f1 + l2*f2 + l3*f3;
    float inv = 1.0f / lstar;
    f32x4 o0 = *(const f32x4*)&po[0][q][l15*4];
    f32x4 o1 = *(const f32x4*)&po[1][q][l15*4];
    f32x4 o2 = *(const f32x4*)&po[2][q][l15*4];
    f32x4 o3 = *(const f32x4*)&po[3][q][l15*4];
    bf16x4 outv;
    #pragma unroll
    for (int j = 0; j < 4; ++j)
      outv[j] = (__bf16)((o0[j]*f0 + o1[j]*f1 + o2[j]*f2 + o3[j]*f3) * inv);
    size_t base = (size_t)(b*TT + q0 + q) * DD + h*HDD + l15*4;
    *(bf16x4*)&y[base] = outv;
  }
}

extern "C" void kernel_launch(void* const* d_in, const int* in_sizes, int n_in,
                              void* d_out, int out_size, void* d_ws, size_t ws_size,
                              hipStream_t stream) {
  const int*   idx    = (const int*)d_in[0];
  const float* clip   = (const float*)d_in[1];
  const float* tok0   = (const float*)d_in[2];
  const float* tok1   = (const float*)d_in[3];
  const float* cond_w = (const float*)d_in[4];
  const float* cond_b = (const float*)d_in[5];
  const float* pos    = (const float*)d_in[6];
  const float* ln1_g  = (const float*)d_in[7];
  const float* ln1_b  = (const float*)d_in[8];
  const float* wq     = (const float*)d_in[9];
  const float* bq     = (const float*)d_in[10];
  const float* wk     = (const float*)d_in[11];
  const float* bk     = (const float*)d_in[12];
  const float* wv     = (const float*)d_in[13];
  const float* bv     = (const float*)d_in[14];
  const float* wo     = (const float*)d_in[15];
  const float* bo     = (const float*)d_in[16];
  const float* ln2_g  = (const float*)d_in[17];
  const float* ln2_b  = (const float*)d_in[18];
  const float* w1     = (const float*)d_in[19];
  const float* b1     = (const float*)d_in[20];
  const float* w2     = (const float*)d_in[21];
  const float* b2     = (const float*)d_in[22];

  float* x = (float*)d_out;
  char* wsb = (char*)d_ws;
  bool bigws = ws_size >= 46153728ULL;

  __bf16* wbuf; __bf16* qkv; __bf16* yb; __bf16* vt; __bf16* ffn;
  size_t wstride;
  if (bigws) {
    wbuf = (__bf16*)wsb;                         // 4 x 6,291,456 B = 25,165,824
    wstride = 3145728;
    qkv  = (__bf16*)(wsb + 29360128);            // 8 MB
    yb   = (__bf16*)(wsb + 37748736);            // 4 MB
    vt   = (__bf16*)(wsb + 41943040);            // 4,210,688 B (ends 46,153,728)
    ffn  = (__bf16*)(wsb + 25165824);            // 16 MB alias over old-h..qkv..yb region start
  } else {
    wbuf = (__bf16*)wsb;
    wstride = 0;
    qkv  = (__bf16*)(wsb + 10485760);
    yb   = (__bf16*)(wsb + 23068672);
    vt   = (__bf16*)(wsb + 27262976);
    ffn  = (__bf16*)(wsb + 6291456);
  }

  embed_kernel<<<dim3(NTOK), 128, 0, stream>>>(idx, tok0, tok1, pos, x);
  cond_kernel<<<dim3(8), 256, 0, stream>>>(clip, cond_w, cond_b, pos, x);

  if (bigws)
    prep_kernel<<<dim3(3072, LL), 256, 0, stream>>>(wq, wk, wv, wo, w1, w2, wbuf, wstride);

  for (int i = 0; i < LL; ++i) {
    __bf16* wb = wbuf + (size_t)i * wstride;
    if (!bigws)
      prep_kernel<<<dim3(3072, 1), 256, 0, stream>>>(
          wq + (size_t)i*262144, wk + (size_t)i*262144, wv + (size_t)i*262144,
          wo + (size_t)i*262144, w1 + (size_t)i*1048576, w2 + (size_t)i*1048576, wb, 0);

    // qkv = ln1(x) @ Wqkv  (LN fused; A = fp32 x)
    mgemm<64,128,1,1,0,0,1><<<dim3(12, 64), 256, 0, stream>>>(
        nullptr, x, ln1_g + i*DD, ln1_b + i*DD, wb,
        bq + i*DD, bk + i*DD, bv + i*DD, nullptr, nullptr, qkv, vt, NTOK, 1536, 512, 1024);

    attn_kernel<<<dim3(1024), 256, 0, stream>>>(qkv, vt, yb);

    mgemm<64,64,0,0,1,0,0><<<dim3(8, 64), 256, 0, stream>>>(
        yb, nullptr, nullptr, nullptr, wb + 786432,
        bo + i*DD, nullptr, nullptr, x, x, nullptr, nullptr, NTOK, 512, 512, 512);

    // ffn = gelu(ln2(x) @ W1)  (LN fused)
    mgemm<64,128,1,0,0,1,1><<<dim3(16, 64), 256, 0, stream>>>(
        nullptr, x, ln2_g + i*DD, ln2_b + i*DD, wb + 1048576,
        b1 + (size_t)i*4*DD, nullptr, nullptr, nullptr, nullptr, ffn, nullptr, NTOK, 4*DD, 512, 2048);

    mgemm<64,64,0,0,1,0,0><<<dim3(8, 64), 256, 0, stream>>>(
        ffn, nullptr, nullptr, nullptr, wb + 2097152,
        b2 + i*DD, nullptr, nullptr, x, x, nullptr, nullptr, NTOK, 512, 2048, 512);
  }
}

// Round 16
// 432.021 us; speedup vs baseline: 1.4702x; 1.4702x over previous
//
#include <hip/hip_runtime.h>
#include <math.h>

#define BB 2
#define TT 2048
#define DD 512
#define LL 4
#define HH 8
#define HDD 64
#define SEMN 50
#define CLIPN 512
#define NTOK (BB*TT)   // 4096
#define QS 1024        // qkv buffer row stride (Q|K only; V goes transposed)
#define VST 2056       // vt key-stride (2048 + 8, breaks 4KB aliasing)

typedef __bf16 bf16x8 __attribute__((ext_vector_type(8)));
typedef __bf16 bf16x4 __attribute__((ext_vector_type(4)));
typedef float  f32x4  __attribute__((ext_vector_type(4)));

#if __has_builtin(__builtin_amdgcn_global_load_lds)
#define USE_GLL 1
#endif

__device__ __forceinline__ void gll16(const __bf16* g, __bf16* l) {
#ifdef USE_GLL
  __builtin_amdgcn_global_load_lds((const __attribute__((address_space(1))) void*)g,
                                   (__attribute__((address_space(3))) void*)l, 16, 0, 0);
#endif
}

__device__ __forceinline__ float fexp2(float x) {
#if __has_builtin(__builtin_amdgcn_exp2f)
  return __builtin_amdgcn_exp2f(x);
#else
  return exp2f(x);
#endif
}

// ---------------- embedding (t>=1 rows): gather + pos, float4 ----------------
__global__ __launch_bounds__(128) void embed_kernel(
    const int* __restrict__ idx,
    const float* __restrict__ tok0, const float* __restrict__ tok1,
    const float* __restrict__ pos, float* __restrict__ x) {
  int row = blockIdx.x;
  int b = row / TT, t = row % TT;
  if (t == 0) return;                  // cond_kernel covers t==0
  int d4 = threadIdx.x << 2;
  int tok = idx[b*(TT-1) + (t-1)];
  const float* te = (t <= SEMN) ? tok0 : tok1;
  float4 e = *(const float4*)&te[(size_t)tok*DD + d4];
  float4 p = *(const float4*)&pos[(size_t)t*DD + d4];
  e.x += p.x; e.y += p.y; e.z += p.z; e.w += p.w;
  *(float4*)&x[(size_t)row*DD + d4] = e;
}

// ---------------- cond matvec (t==0 rows): k-split 8x + LDS reduce ----------------
__global__ __launch_bounds__(256) void cond_kernel(
    const float* __restrict__ clip, const float* __restrict__ cw,
    const float* __restrict__ cb, const float* __restrict__ pos,
    float* __restrict__ x) {
  __shared__ float4 part[8][32];
  int b = blockIdx.x >> 2, dc = blockIdx.x & 3;   // d-chunk of 128
  int tid = threadIdx.x;
  int dv = tid & 31;                  // float4 index within chunk
  int cg = tid >> 5;                  // k-group 0..7 (64 c each)
  int d4 = dc*128 + dv*4;
  const float* cr = clip + b*CLIPN + cg*64;
  float4 acc = {0.f, 0.f, 0.f, 0.f};
  #pragma unroll 8
  for (int i = 0; i < 64; ++i) {
    float cv = cr[i];
    float4 w4 = *(const float4*)&cw[(size_t)(cg*64 + i)*DD + d4];
    acc.x = fmaf(cv, w4.x, acc.x); acc.y = fmaf(cv, w4.y, acc.y);
    acc.z = fmaf(cv, w4.z, acc.z); acc.w = fmaf(cv, w4.w, acc.w);
  }
  part[cg][dv] = acc;
  __syncthreads();
  if (tid < 32) {
    int dd4 = dc*128 + tid*4;
    float4 s = part[0][tid];
    #pragma unroll
    for (int g = 1; g < 8; ++g) {
      float4 q = part[g][tid];
      s.x += q.x; s.y += q.y; s.z += q.z; s.w += q.w;
    }
    float4 cbv = *(const float4*)&cb[dd4];
    float4 pv  = *(const float4*)&pos[dd4];      // pos row 0
    s.x += cbv.x + pv.x; s.y += cbv.y + pv.y;
    s.z += cbv.z + pv.z; s.w += cbv.w + pv.w;
    *(float4*)&x[(size_t)(b*TT)*DD + dd4] = s;
  }
}

// ---------------- layernorm: fp32 in -> bf16 out; wave per row, no LDS/barriers ----------------
__global__ __launch_bounds__(256) void ln_kernel(const float* __restrict__ x,
                                                 const float* __restrict__ g,
                                                 const float* __restrict__ bta,
                                                 __bf16* __restrict__ out) {
  int l = threadIdx.x & 63;
  int row = blockIdx.x * 4 + (threadIdx.x >> 6);
  const float* xr = x + (size_t)row * DD + l*8;
  f32x4 a = *(const f32x4*)xr;
  f32x4 c = *(const f32x4*)(xr + 4);
  float s = a[0]+a[1]+a[2]+a[3]+c[0]+c[1]+c[2]+c[3];
  #pragma unroll
  for (int off = 1; off < 64; off <<= 1) s += __shfl_xor(s, off);
  float mean = s * (1.0f / DD);
  float d0 = a[0]-mean, d1 = a[1]-mean, d2 = a[2]-mean, d3 = a[3]-mean;
  float d4 = c[0]-mean, d5 = c[1]-mean, d6 = c[2]-mean, d7 = c[3]-mean;
  float sv = d0*d0+d1*d1+d2*d2+d3*d3+d4*d4+d5*d5+d6*d6+d7*d7;
  #pragma unroll
  for (int off = 1; off < 64; off <<= 1) sv += __shfl_xor(sv, off);
  float r = rsqrtf(sv * (1.0f / DD) + 1e-5f);
  f32x4 gv0 = *(const f32x4*)&g[l*8],   gv1 = *(const f32x4*)&g[l*8+4];
  f32x4 bv0 = *(const f32x4*)&bta[l*8], bv1 = *(const f32x4*)&bta[l*8+4];
  bf16x8 o;
  o[0] = (__bf16)(d0*r*gv0[0] + bv0[0]); o[1] = (__bf16)(d1*r*gv0[1] + bv0[1]);
  o[2] = (__bf16)(d2*r*gv0[2] + bv0[2]); o[3] = (__bf16)(d3*r*gv0[3] + bv0[3]);
  o[4] = (__bf16)(d4*r*gv1[0] + bv1[0]); o[5] = (__bf16)(d5*r*gv1[1] + bv1[1]);
  o[6] = (__bf16)(d6*r*gv1[2] + bv1[2]); o[7] = (__bf16)(d7*r*gv1[3] + bv1[3]);
  *(bf16x8*)&out[(size_t)row*DD + l*8] = o;
}

// ---------------- weight transpose+convert: [K,N] f32 -> [N,K] bf16; gridDim.y = layers ----------------
__global__ __launch_bounds__(256) void prep_kernel(
    const float* __restrict__ wq, const float* __restrict__ wk,
    const float* __restrict__ wv, const float* __restrict__ wo,
    const float* __restrict__ w1, const float* __restrict__ w2,
    __bf16* __restrict__ wbuf, size_t dstride) {
  __shared__ float tile[32][33];
  int id = blockIdx.x;
  int lay = blockIdx.y;
  size_t so4 = (size_t)lay * 262144, so16 = (size_t)lay * 1048576;
  __bf16* wb = wbuf + (size_t)lay * dstride;
  const float* src; __bf16* dst; int K, N, t;
  if (id < 1024) {
    int m = id >> 8; t = id & 255;
    src = ((m==0) ? wq : (m==1) ? wk : (m==2) ? wv : wo) + so4;
    dst = wb + (size_t)m * 262144; K = 512; N = 512;
  } else if (id < 2048) {
    t = id - 1024; src = w1 + so16; dst = wb + 1048576; K = 512; N = 2048;
  } else {
    t = id - 2048; src = w2 + so16; dst = wb + 2097152; K = 2048; N = 512;
  }
  int nsh = (N == 2048) ? 6 : 4;
  int tk = t >> nsh, tn = t & ((1 << nsh) - 1);
  int k0 = tk << 5, n0 = tn << 5;
  int tid = threadIdx.x;
  int r = tid >> 3, c = (tid & 7) << 2;
  float4 v = *(const float4*)&src[(size_t)(k0 + r)*N + n0 + c];
  tile[r][c+0] = v.x; tile[r][c+1] = v.y; tile[r][c+2] = v.z; tile[r][c+3] = v.w;
  __syncthreads();
  bf16x4 o;
  o[0] = (__bf16)tile[c+0][r];
  o[1] = (__bf16)tile[c+1][r];
  o[2] = (__bf16)tile[c+2][r];
  o[3] = (__bf16)tile[c+3][r];
  *(bf16x4*)&dst[(size_t)(n0 + r)*K + k0 + c] = o;
}

// ---------------- bf16 MFMA GEMM, BK=64, single-buffer (best-known R12 structure) ----------------
// 8-slot XOR swizzle (slot ^ row&7) applied on global source for GLL (rule 21).
template<int TM, int TN, int QKV3, int RES, int GEL, int OB>
__global__ __launch_bounds__(256) void mgemm(
    const __bf16* __restrict__ A, const __bf16* __restrict__ Bt,
    const float* __restrict__ b0, const float* __restrict__ b1p, const float* __restrict__ b2p,
    const float* __restrict__ res, float* __restrict__ outF, __bf16* __restrict__ outB,
    __bf16* __restrict__ vtOut, int M, int N, int K, int ldo) {
  __shared__ __bf16 As[TM*64];
  __shared__ __bf16 Bs[TN*64];
  int tid = threadIdx.x, wave = tid >> 6, l = tid & 63;
  int l15 = l & 15, lg = l >> 4;
  int m0 = blockIdx.y * TM, n0 = blockIdx.x * TN;
  constexpr int WR = (TM == 128) ? 2 : 1;
  constexpr int WC = 4 / WR;
  constexpr int FM = TM / (16 * WR);
  constexpr int FN = TN / (16 * WC);
  int wr = wave / WC;
  int wc = wave % WC;

  f32x4 acc[FM][FN] = {};

  for (int k0 = 0; k0 < K; k0 += 64) {
#ifdef USE_GLL
    __syncthreads();    // previous tile consumed
    #pragma unroll
    for (int g = wave; g < TM/8; g += 4) {
      int row = g*8 + (l >> 3);
      int lslot = (l & 7) ^ (row & 7);
      gll16(A + (size_t)(m0+row)*K + k0 + lslot*8, &As[g*512]);
    }
    #pragma unroll
    for (int g = wave; g < TN/8; g += 4) {
      int row = g*8 + (l >> 3);
      int lslot = (l & 7) ^ (row & 7);
      gll16(Bt + (size_t)(n0+row)*K + k0 + lslot*8, &Bs[g*512]);
    }
    asm volatile("s_waitcnt vmcnt(0)" ::: "memory");
    __syncthreads();
#else
    bf16x8 ar[TM/32], br[TN/32];
    #pragma unroll
    for (int c = 0; c < TM/32; ++c) {
      int idx = tid + c*256;
      int row = idx >> 3;
      int lslot = (idx & 7) ^ (row & 7);
      ar[c] = *(const bf16x8*)(A + (size_t)(m0+row)*K + k0 + lslot*8);
    }
    #pragma unroll
    for (int c = 0; c < TN/32; ++c) {
      int idx = tid + c*256;
      int row = idx >> 3;
      int lslot = (idx & 7) ^ (row & 7);
      br[c] = *(const bf16x8*)(Bt + (size_t)(n0+row)*K + k0 + lslot*8);
    }
    __syncthreads();
    #pragma unroll
    for (int c = 0; c < TM/32; ++c) {
      int idx = tid + c*256;
      *(bf16x8*)&As[(idx >> 3)*64 + (idx & 7)*8] = ar[c];
    }
    #pragma unroll
    for (int c = 0; c < TN/32; ++c) {
      int idx = tid + c*256;
      *(bf16x8*)&Bs[(idx >> 3)*64 + (idx & 7)*8] = br[c];
    }
    __syncthreads();
#endif
    bf16x8 af[FM][2], bfr[FN][2];
    #pragma unroll
    for (int mi = 0; mi < FM; ++mi) {
      int row = (wr*FM + mi)*16 + l15;
      #pragma unroll
      for (int h = 0; h < 2; ++h) {
        int ps = (h*4 + lg) ^ (row & 7);
        af[mi][h] = *(const bf16x8*)&As[row*64 + ps*8];
      }
    }
    #pragma unroll
    for (int ni = 0; ni < FN; ++ni) {
      int row = (wc*FN + ni)*16 + l15;
      #pragma unroll
      for (int h = 0; h < 2; ++h) {
        int ps = (h*4 + lg) ^ (row & 7);
        bfr[ni][h] = *(const bf16x8*)&Bs[row*64 + ps*8];
      }
    }
    #pragma unroll
    for (int mi = 0; mi < FM; ++mi)
      #pragma unroll
      for (int ni = 0; ni < FN; ++ni) {
        acc[mi][ni] = __builtin_amdgcn_mfma_f32_16x16x32_bf16(af[mi][0], bfr[ni][0], acc[mi][ni], 0, 0, 0);
        acc[mi][ni] = __builtin_amdgcn_mfma_f32_16x16x32_bf16(af[mi][1], bfr[ni][1], acc[mi][ni], 0, 0, 0);
      }
  }

  #pragma unroll
  for (int mi = 0; mi < FM; ++mi) {
    #pragma unroll
    for (int ni = 0; ni < FN; ++ni) {
      int col = n0 + (wc*FN + ni)*16 + l15;
      float bs;
      if (QKV3) bs = (col < 512) ? b0[col] : (col < 1024) ? b1p[col-512] : b2p[col-1024];
      else bs = b0[col];
      int row0 = m0 + (wr*FM + mi)*16 + (lg << 2);
      if (QKV3 && col >= 1024) {
        int hdg = col - 1024;
        bf16x4 pk;
        #pragma unroll
        for (int r = 0; r < 4; ++r) pk[r] = (__bf16)(acc[mi][ni][r] + bs);
        size_t vrow = (size_t)(((row0 >> 11)*8 + (hdg >> 6))*64 + (hdg & 63));
        *(bf16x4*)&vtOut[vrow*VST + (row0 & 2047)] = pk;
      } else {
        #pragma unroll
        for (int r = 0; r < 4; ++r) {
          int row = row0 + r;
          float v = acc[mi][ni][r] + bs;
          if (RES) v += res[(size_t)row*ldo + col];
          if (GEL) v = 0.5f * v * (1.0f + erff(v * 0.70710678118654752f));
          if (OB) outB[(size_t)row*ldo + col] = (__bf16)v;
          else    outF[(size_t)row*ldo + col] = v;
        }
      }
    }
  }
}

// ---------------- flash attention: block = (b,h,32 q-rows), 4 waves key-split, KVBLK=64 ----------------
// Single K reg-buffer with EARLY RE-ISSUE: QK consumes kf first, next KLOAD issues immediately
// after (latency hides under mask+softmax+PV). Per-fragment softmax+PV shortens sv liveness.
__global__ __launch_bounds__(256) void attn_kernel(const __bf16* __restrict__ qkv,
                                                   const __bf16* __restrict__ vt,
                                                   __bf16* __restrict__ y) {
  __shared__ float po[4][32][68];
  __shared__ float pmS[4][32];
  __shared__ float plS[4][4][32];
  int tid = threadIdx.x, wave = tid >> 6, l = tid & 63;
  int l15 = l & 15, lg = l >> 4;

  int wid = blockIdx.x;                // 0..1023, longest-first
  int g2 = 63 - (wid >> 4);            // 32-row q-group within (b,h)
  int bh = wid & 15;
  int b = bh >> 3, h = bh & 7;
  int q0 = g2 * 32;

  const __bf16* qp = qkv + (size_t)(b*TT)*QS + h*HDD;
  const __bf16* kp = qp + 512;
  const __bf16* vtp = vt + ((size_t)bh*64 + l15)*VST + lg*8;
  const __bf16* kbase = kp + (size_t)l15*QS + lg*8;

  // Q fragments, pre-scaled by log2(e)/sqrt(64)
  bf16x8 qf[2][2];
  {
    const float qs = 0.125f * 1.44269504088896f;
    #pragma unroll
    for (int f = 0; f < 2; ++f) {
      size_t qr = (size_t)(q0 + f*16 + l15) * QS + lg*8;
      bf16x8 t0 = *(const bf16x8*)(qp + qr);
      bf16x8 t1 = *(const bf16x8*)(qp + qr + 32);
      #pragma unroll
      for (int e = 0; e < 8; ++e) {
        qf[f][0][e] = (__bf16)((float)t0[e] * qs);
        qf[f][1][e] = (__bf16)((float)t1[e] * qs);
      }
    }
  }

  f32x4 o[2][4] = {};
  float m0 = 0.f, m1 = 0.f, ls0 = 0.f, ls1 = 0.f;
  int qpos0 = q0 + l15, qpos1 = q0 + 16 + l15;
  int nt = (q0 + 95) >> 6;             // ceil((q0+32)/64)
  int cs = (nt + 3) >> 2;
  int t0w = wave * cs;
  int t1w = t0w + cs; if (t1w > nt) t1w = nt;

  bf16x8 kf[4][2], vv[8];

#define KLOAD(KT) do {                                              \
    const __bf16* kr_ = kbase + (size_t)(KT)*64*QS;                 \
    _Pragma("unroll")                                               \
    for (int j_ = 0; j_ < 4; ++j_) {                                \
      kf[j_][0] = *(const bf16x8*)(kr_ + j_*16*QS);                 \
      kf[j_][1] = *(const bf16x8*)(kr_ + j_*16*QS + 32);            \
    }                                                               \
  } while (0)

#define VLOAD(KT) do {                                              \
    const __bf16* vr_ = vtp + (KT)*64;                              \
    _Pragma("unroll")                                               \
    for (int hc_ = 0; hc_ < 4; ++hc_) {                             \
      vv[hc_]     = *(const bf16x8*)(vr_ + hc_*16*VST);             \
      vv[hc_ + 4] = *(const bf16x8*)(vr_ + hc_*16*VST + 32);        \
    }                                                               \
  } while (0)

  if (t0w < t1w) {
    KLOAD(t0w);
    for (int kt = t0w; kt < t1w; ++kt) {
      VLOAD(kt);
      // ---- QK^T for both fragments (kf dead after this) ----
      float sv[2][4][4];
      #pragma unroll
      for (int f = 0; f < 2; ++f)
        #pragma unroll
        for (int j = 0; j < 4; ++j) {
          f32x4 a_ = {};
          a_ = __builtin_amdgcn_mfma_f32_16x16x32_bf16(kf[j][0], qf[f][0], a_, 0, 0, 0);
          a_ = __builtin_amdgcn_mfma_f32_16x16x32_bf16(kf[j][1], qf[f][1], a_, 0, 0, 0);
          #pragma unroll
          for (int r = 0; r < 4; ++r) sv[f][j][r] = a_[r];
        }
      // ---- early re-issue of next K tile; latency covered by softmax+PV below ----
      if (kt + 1 < t1w) KLOAD(kt + 1);
      // ---- causal mask (only the boundary tile needs it) ----
      if (kt == nt - 1) {
        #pragma unroll
        for (int j = 0; j < 4; ++j) {
          int kb0 = kt*64 + j*16 + lg*4;
          #pragma unroll
          for (int r = 0; r < 4; ++r) {
            if (kb0 + r > qpos0) sv[0][j][r] = -1e30f;
            if (kb0 + r > qpos1) sv[1][j][r] = -1e30f;
          }
        }
      }
      // ---- per-fragment softmax + PV ----
      #pragma unroll
      for (int f = 0; f < 2; ++f) {
        float& m  = f ? m1 : m0;
        float& ls = f ? ls1 : ls0;
        float px = sv[f][0][0];
        #pragma unroll
        for (int j = 0; j < 4; ++j)
          #pragma unroll
          for (int r = 0; r < 4; ++r) px = fmaxf(px, sv[f][j][r]);
        if (!__all(px - m <= 8.0f)) {
          float u = px, w = px;
          asm("v_permlane32_swap_b32 %0, %1" : "+v"(u), "+v"(w));
          float t_ = fmaxf(u, w); u = t_; w = t_;
          asm("v_permlane16_swap_b32 %0, %1" : "+v"(u), "+v"(w));
          float tm = fmaxf(u, w);
          float mn = fmaxf(m, tm);
          float fc = fexp2(m - mn);
          m = mn; ls *= fc;
          float f0_ = __shfl(fc, lg*4+0), f1_ = __shfl(fc, lg*4+1);
          float f2_ = __shfl(fc, lg*4+2), f3_ = __shfl(fc, lg*4+3);
          #pragma unroll
          for (int hc = 0; hc < 4; ++hc) {
            o[f][hc][0] *= f0_; o[f][hc][1] *= f1_;
            o[f][hc][2] *= f2_; o[f][hc][3] *= f3_;
          }
        }
        float p_[4][4];
        float rs = 0.f;
        #pragma unroll
        for (int j = 0; j < 4; ++j)
          #pragma unroll
          for (int r = 0; r < 4; ++r) { p_[j][r] = fexp2(sv[f][j][r] - m); rs += p_[j][r]; }
        ls += rs;
        union PU { unsigned u[4]; bf16x8 v; };
        PU pa0, pa1;
        #pragma unroll
        for (int pair = 0; pair < 2; ++pair) {
          unsigned c0, c1, d0, d1;
          asm("v_cvt_pk_bf16_f32 %0, %1, %2" : "=v"(c0) : "v"(p_[2*pair][0]),   "v"(p_[2*pair][1]));
          asm("v_cvt_pk_bf16_f32 %0, %1, %2" : "=v"(c1) : "v"(p_[2*pair][2]),   "v"(p_[2*pair][3]));
          asm("v_cvt_pk_bf16_f32 %0, %1, %2" : "=v"(d0) : "v"(p_[2*pair+1][0]), "v"(p_[2*pair+1][1]));
          asm("v_cvt_pk_bf16_f32 %0, %1, %2" : "=v"(d1) : "v"(p_[2*pair+1][2]), "v"(p_[2*pair+1][3]));
          asm("v_permlane32_swap_b32 %0, %1" : "+v"(c0), "+v"(d0));
          asm("v_permlane32_swap_b32 %0, %1" : "+v"(c1), "+v"(d1));
          asm("v_permlane16_swap_b32 %0, %1" : "+v"(c0), "+v"(d0));
          asm("v_permlane16_swap_b32 %0, %1" : "+v"(c1), "+v"(d1));
          PU& pa = pair ? pa1 : pa0;
          pa.u[0] = c0; pa.u[1] = c1; pa.u[2] = d0; pa.u[3] = d1;
        }
        #pragma unroll
        for (int hc = 0; hc < 4; ++hc) {
          o[f][hc] = __builtin_amdgcn_mfma_f32_16x16x32_bf16(pa0.v, vv[hc],     o[f][hc], 0, 0, 0);
          o[f][hc] = __builtin_amdgcn_mfma_f32_16x16x32_bf16(pa1.v, vv[hc + 4], o[f][hc], 0, 0, 0);
        }
      }
    }
  }

  // ---- write partials ----
  #pragma unroll
  for (int f = 0; f < 2; ++f)
    #pragma unroll
    for (int hc = 0; hc < 4; ++hc)
      #pragma unroll
      for (int r = 0; r < 4; ++r)
        po[wave][f*16 + lg*4 + r][hc*16 + l15] = o[f][hc][r];
  plS[wave][lg][l15]      = ls0;
  plS[wave][lg][16 + l15] = ls1;
  if (l < 16) { pmS[wave][l] = m0; pmS[wave][16 + l] = m1; }
  __syncthreads();

  // ---- flash merge (exp2 domain), two q-rows per thread ----
  #pragma unroll
  for (int rep = 0; rep < 2; ++rep) {
    int q = wave*4 + lg + rep*16;
    float e0 = pmS[0][q], e1 = pmS[1][q], e2 = pmS[2][q], e3 = pmS[3][q];
    float mstar = fmaxf(fmaxf(e0, e1), fmaxf(e2, e3));
    float f0 = fexp2(e0 - mstar), f1 = fexp2(e1 - mstar);
    float f2 = fexp2(e2 - mstar), f3 = fexp2(e3 - mstar);
    float l0 = plS[0][0][q] + plS[0][1][q] + plS[0][2][q] + plS[0][3][q];
    float l1 = plS[1][0][q] + plS[1][1][q] + plS[1][2][q] + plS[1][3][q];
    float l2 = plS[2][0][q] + plS[2][1][q] + plS[2][2][q] + plS[2][3][q];
    float l3 = plS[3][0][q] + plS[3][1][q] + plS[3][2][q] + plS[3][3][q];
    float lstar = l0*f0 + l1*f1 + l2*f2 + l3*f3;
    float inv = 1.0f / lstar;
    f32x4 o0 = *(const f32x4*)&po[0][q][l15*4];
    f32x4 o1 = *(const f32x4*)&po[1][q][l15*4];
    f32x4 o2 = *(const f32x4*)&po[2][q][l15*4];
    f32x4 o3 = *(const f32x4*)&po[3][q][l15*4];
    bf16x4 outv;
    #pragma unroll
    for (int j = 0; j < 4; ++j)
      outv[j] = (__bf16)((o0[j]*f0 + o1[j]*f1 + o2[j]*f2 + o3[j]*f3) * inv);
    size_t base = (size_t)(b*TT + q0 + q) * DD + h*HDD + l15*4;
    *(bf16x4*)&y[base] = outv;
  }
}

extern "C" void kernel_launch(void* const* d_in, const int* in_sizes, int n_in,
                              void* d_out, int out_size, void* d_ws, size_t ws_size,
                              hipStream_t stream) {
  const int*   idx    = (const int*)d_in[0];
  const float* clip   = (const float*)d_in[1];
  const float* tok0   = (const float*)d_in[2];
  const float* tok1   = (const float*)d_in[3];
  const float* cond_w = (const float*)d_in[4];
  const float* cond_b = (const float*)d_in[5];
  const float* pos    = (const float*)d_in[6];
  const float* ln1_g  = (const float*)d_in[7];
  const float* ln1_b  = (const float*)d_in[8];
  const float* wq     = (const float*)d_in[9];
  const float* bq     = (const float*)d_in[10];
  const float* wk     = (const float*)d_in[11];
  const float* bk     = (const float*)d_in[12];
  const float* wv     = (const float*)d_in[13];
  const float* bv     = (const float*)d_in[14];
  const float* wo     = (const float*)d_in[15];
  const float* bo     = (const float*)d_in[16];
  const float* ln2_g  = (const float*)d_in[17];
  const float* ln2_b  = (const float*)d_in[18];
  const float* w1     = (const float*)d_in[19];
  const float* b1     = (const float*)d_in[20];
  const float* w2     = (const float*)d_in[21];
  const float* b2     = (const float*)d_in[22];

  float* x = (float*)d_out;
  char* wsb = (char*)d_ws;
  bool bigws = ws_size >= 46153728ULL;

  __bf16* wbuf; __bf16* h; __bf16* qkv; __bf16* yb; __bf16* vt; __bf16* ffn;
  size_t wstride;
  if (bigws) {
    wbuf = (__bf16*)wsb;                         // 4 x 6,291,456 B = 25,165,824
    wstride = 3145728;
    h    = (__bf16*)(wsb + 25165824);            // 4 MB
    qkv  = (__bf16*)(wsb + 29360128);            // 8 MB
    yb   = (__bf16*)(wsb + 37748736);            // 4 MB
    vt   = (__bf16*)(wsb + 41943040);            // 4,210,688 B (ends 46,153,728)
    ffn  = qkv;                                  // 16 MB alias
  } else {
    wbuf = (__bf16*)wsb;
    wstride = 0;
    h    = (__bf16*)(wsb + 6291456);
    qkv  = (__bf16*)(wsb + 10485760);
    yb   = (__bf16*)(wsb + 23068672);
    vt   = (__bf16*)(wsb + 27262976);
    ffn  = qkv;
  }

  embed_kernel<<<dim3(NTOK), 128, 0, stream>>>(idx, tok0, tok1, pos, x);
  cond_kernel<<<dim3(8), 256, 0, stream>>>(clip, cond_w, cond_b, pos, x);

  if (bigws)
    prep_kernel<<<dim3(3072, LL), 256, 0, stream>>>(wq, wk, wv, wo, w1, w2, wbuf, wstride);

  for (int i = 0; i < LL; ++i) {
    __bf16* wb = wbuf + (size_t)i * wstride;
    if (!bigws)
      prep_kernel<<<dim3(3072, 1), 256, 0, stream>>>(
          wq + (size_t)i*262144, wk + (size_t)i*262144, wv + (size_t)i*262144,
          wo + (size_t)i*262144, w1 + (size_t)i*1048576, w2 + (size_t)i*1048576, wb, 0);

    ln_kernel<<<NTOK/4, 256, 0, stream>>>(x, ln1_g + i*DD, ln1_b + i*DD, h);

    mgemm<64,128,1,0,0,1><<<dim3(12, 64), 256, 0, stream>>>(
        h, wb, bq + i*DD, bk + i*DD, bv + i*DD, nullptr, nullptr, qkv, vt, NTOK, 1536, 512, 1024);

    attn_kernel<<<dim3(1024), 256, 0, stream>>>(qkv, vt, yb);

    mgemm<64,64,0,1,0,0><<<dim3(8, 64), 256, 0, stream>>>(
        yb, wb + 786432, bo + i*DD, nullptr, nullptr, x, x, nullptr, nullptr, NTOK, 512, 512, 512);

    ln_kernel<<<NTOK/4, 256, 0, stream>>>(x, ln2_g + i*DD, ln2_b + i*DD, h);

    mgemm<128,128,0,0,1,1><<<dim3(16, 32), 256, 0, stream>>>(
        h, wb + 1048576, b1 + (size_t)i*4*DD, nullptr, nullptr, nullptr, nullptr, ffn, nullptr, NTOK, 4*DD, 512, 2048);

    mgemm<64,64,0,1,0,0><<<dim3(8, 64), 256, 0, stream>>>(
        ffn, wb + 2097152, b2 + i*DD, nullptr, nullptr, x, x, nullptr, nullptr, NTOK, 512, 2048, 512);
  }
}